// Round 2
// baseline (608.635 us; speedup 1.0000x reference)
//
#include <hip/hip_runtime.h>
#include <hip/hip_bf16.h>

// CrossAttention: 3 heads, B=8, LQ=LK=1024, H=768.
// Pipeline: cvt -> transpose weights -> QKV gemms (fp16 MFMA) -> fused attention -> out gemm.
// fp16 (not bf16) internally: 11-bit mantissa keeps logit error ~0.006 std vs 0.05 for bf16,
// which is what the 2.39e-2 absmax threshold demands (R0 post-mortem).

typedef _Float16 f16;
typedef __attribute__((ext_vector_type(8))) _Float16 f16x8;
typedef __attribute__((ext_vector_type(4))) float f32x4;
typedef __attribute__((ext_vector_type(4))) short s16x4;

#define DI __device__ __forceinline__

DI short f2hs(float f){
  f16 h = (f16)f;                       // RNE
  return __builtin_bit_cast(short, h);
}

DI f32x4 mfma16(f16x8 a, f16x8 b, f32x4 c){
  return __builtin_amdgcn_mfma_f32_16x16x32_f16(a, b, c, 0, 0, 0);
}

#define GLL16(gp, lp) __builtin_amdgcn_global_load_lds( \
    (const __attribute__((address_space(1))) unsigned int*)(gp), \
    (__attribute__((address_space(3))) unsigned int*)(lp), 16, 0, 0)

// ---------------- elementwise f32 -> fp16 ----------------
__global__ void cvt_f16_kernel(const float* __restrict__ in, short* __restrict__ out, int n4){
  int i = blockIdx.x * blockDim.x + threadIdx.x;
  if (i >= n4) return;
  f32x4 v = ((const f32x4*)in)[i];
  s16x4 o;
  o[0]=f2hs(v[0]); o[1]=f2hs(v[1]); o[2]=f2hs(v[2]); o[3]=f2hs(v[3]);
  ((s16x4*)out)[i] = o;
}

// ---------------- transpose + convert: fp32 [R][C] -> fp16 [C][R] ----------------
__global__ void transpose_cvt_kernel(const float* __restrict__ in, short* __restrict__ out, int R, int C){
  __shared__ float tile[32][33];
  long zoff = (long)blockIdx.z * R * C;
  in += zoff; out += zoff;
  int c0 = blockIdx.x * 32, r0 = blockIdx.y * 32;
  int tx = threadIdx.x, ty = threadIdx.y;
  #pragma unroll
  for (int k=0;k<4;k++)
    tile[ty + k*8][tx] = in[(long)(r0 + ty + k*8) * C + c0 + tx];
  __syncthreads();
  #pragma unroll
  for (int k=0;k<4;k++)
    out[(long)(c0 + ty + k*8) * R + r0 + tx] = f2hs(tile[tx][ty + k*8]);
}

// ---------------- shared 128x128 GEMM core (A [M,K] f16, Bt [N,K] f16) ----------------
DI void gemm_tile(const short* __restrict__ A, const short* __restrict__ Bt, int K,
                  int m0, int n0, short* As, short* Bs, f32x4 (&acc)[4][4])
{
  const int tid = threadIdx.x, wave = tid>>6, lane = tid&63;
  const int wm = wave>>1, wn = wave&1;
  const int fl = lane&15, fq = lane>>4;
  const int srow = lane>>2, scol = (lane&3)*8;
  for (int kk=0; kk<K; kk+=32){
    __syncthreads();
    #pragma unroll
    for (int r=0;r<2;r++){
      const int rb = r*64 + wave*16;
      GLL16(A  + (long)(m0+rb+srow)*K + kk + scol, As + rb*32);
      GLL16(Bt + (long)(n0+rb+srow)*K + kk + scol, Bs + rb*32);
    }
    __syncthreads();
    f16x8 a[4];
    #pragma unroll
    for (int i=0;i<4;i++) a[i] = *(const f16x8*)(As + (wm*64+i*16+fl)*32 + fq*8);
    #pragma unroll
    for (int j=0;j<4;j++){
      f16x8 b = *(const f16x8*)(Bs + (wn*64+j*16+fl)*32 + fq*8);
      #pragma unroll
      for (int i=0;i<4;i++) acc[i][j] = mfma16(a[i], b, acc[i][j]);
    }
  }
}

// ---------------- QKV projection: z = which*3 + h; V stored transposed ----------------
__global__ __launch_bounds__(256,2) void gemm_qkv_kernel(
    const short* __restrict__ t1b, const short* __restrict__ t2b,
    const short* __restrict__ WqT, const short* __restrict__ WkT, const short* __restrict__ WvT,
    const float* __restrict__ bq, const float* __restrict__ bk, const float* __restrict__ bv,
    short* __restrict__ Qb, short* __restrict__ Kb, short* __restrict__ Vtb)
{
  __shared__ short As[128*32];
  __shared__ short Bs[128*32];
  const int z = blockIdx.z;
  const int h = z % 3, which = z / 3;
  const short* A  = (which==0) ? t1b : t2b;
  const short* Bt = ((which==0)?WqT:(which==1)?WkT:WvT) + h*768*768;
  const float* bias = ((which==0)?bq:(which==1)?bk:bv) + h*768;
  const int m0 = blockIdx.x*128, n0 = blockIdx.y*128;
  const int tid = threadIdx.x, wave = tid>>6, lane = tid&63;
  const int wm = wave>>1, wn = wave&1;
  const int fl = lane&15, fq = lane>>4;

  f32x4 vz = {0.f,0.f,0.f,0.f};
  f32x4 acc[4][4];
  #pragma unroll
  for (int i=0;i<4;i++)
    #pragma unroll
    for (int j=0;j<4;j++) acc[i][j] = vz;

  gemm_tile(A, Bt, 768, m0, n0, As, Bs, acc);

  if (which < 2){
    short* outp = (which==0 ? Qb : Kb) + (long)h*8192*768;
    #pragma unroll
    for (int j=0;j<4;j++){
      int col = n0 + wn*64 + j*16 + fl;
      float bb = bias[col];
      #pragma unroll
      for (int i=0;i<4;i++){
        int row = m0 + wm*64 + i*16 + fq*4;
        #pragma unroll
        for (int r=0;r<4;r++)
          outp[(long)(row+r)*768 + col] = f2hs(acc[i][j][r] + bb);
      }
    }
  } else {
    const int bidx = m0 >> 10;       // 128-row block never crosses a batch boundary
    const int lk0  = m0 & 1023;
    short* outp = Vtb + (long)(h*8 + bidx)*768*1024;
    #pragma unroll
    for (int j=0;j<4;j++){
      int e = n0 + wn*64 + j*16 + fl;
      float bb = bias[e];
      #pragma unroll
      for (int i=0;i<4;i++){
        int lk = lk0 + wm*64 + i*16 + fq*4;
        s16x4 pack;
        #pragma unroll
        for (int r=0;r<4;r++) pack[r] = f2hs(acc[i][j][r] + bb);
        *(s16x4*)(outp + (long)e*1024 + lk) = pack;
      }
    }
  }
}

// ---------------- fused attention: scores + softmax + PV + relu ----------------
// grid (32 qtiles, 8 batches, 3 heads), 256 threads. 32 Q-rows per block.
__global__ __launch_bounds__(256,2) void attn_kernel(
    const short* __restrict__ Qb, const short* __restrict__ Kb,
    const short* __restrict__ Vtb, short* __restrict__ multi)
{
  __shared__ short Ps[32768];   // 64KB: P in A-frag layout [kc=k/8][m=32][8]
  const int q0 = blockIdx.x*32, b = blockIdx.y, h = blockIdx.z;
  const int tid = threadIdx.x, wave = tid>>6, lane = tid&63;
  const int fl = lane&15, fq = lane>>4;
  const long qkbase = ((long)h*8192 + b*1024) * 768;
  const short* Qp = Qb + qkbase + (long)q0*768;
  const short* Kp = Kb + qkbase;
  const short* Vp = Vtb + (long)(h*8+b)*768*1024;

  // ---- phase 1: S[32][1024], wave w owns cols [w*256, w*256+256) ----
  f32x4 vz = {0.f,0.f,0.f,0.f};
  f32x4 accs[2][16];
  #pragma unroll
  for (int i=0;i<2;i++)
    #pragma unroll
    for (int j=0;j<16;j++) accs[i][j] = vz;

  for (int kk=0; kk<768; kk+=32){
    f16x8 aq[2];
    #pragma unroll
    for (int i=0;i<2;i++)
      aq[i] = *(const f16x8*)(Qp + (long)(i*16+fl)*768 + kk + fq*8);
    #pragma unroll
    for (int j=0;j<16;j++){
      f16x8 bk_ = *(const f16x8*)(Kp + (long)(wave*256 + j*16 + fl)*768 + kk + fq*8);
      #pragma unroll
      for (int i=0;i<2;i++) accs[i][j] = mfma16(aq[i], bk_, accs[i][j]);
    }
  }

  // ---- softmax (fp32). Cross-wave reductions through a 512B scratch corner of Ps. ----
  float* scratch = (float*)Ps;
  float gmax[2][4], inv[2][4];
  #pragma unroll
  for (int i=0;i<2;i++)
    #pragma unroll
    for (int r=0;r<4;r++){
      float m = accs[i][0][r];
      #pragma unroll
      for (int j=1;j<16;j++) m = fmaxf(m, accs[i][j][r]);
      m = fmaxf(m, __shfl_xor(m, 1));
      m = fmaxf(m, __shfl_xor(m, 2));
      m = fmaxf(m, __shfl_xor(m, 4));
      m = fmaxf(m, __shfl_xor(m, 8));
      if (fl == 0) scratch[wave*32 + i*16 + fq*4 + r] = m;
    }
  __syncthreads();
  #pragma unroll
  for (int i=0;i<2;i++)
    #pragma unroll
    for (int r=0;r<4;r++){
      int row = i*16 + fq*4 + r;
      gmax[i][r] = fmaxf(fmaxf(scratch[row], scratch[32+row]),
                         fmaxf(scratch[64+row], scratch[96+row]));
    }
  __syncthreads();   // scratch reads done before reuse for sums

  float rsum[2][4] = {};
  #pragma unroll
  for (int i=0;i<2;i++)
    #pragma unroll
    for (int j=0;j<16;j++)
      #pragma unroll
      for (int r=0;r<4;r++){
        float p = __expf(accs[i][j][r] - gmax[i][r]);
        accs[i][j][r] = p;
        rsum[i][r] += p;
      }
  #pragma unroll
  for (int i=0;i<2;i++)
    #pragma unroll
    for (int r=0;r<4;r++){
      float s = rsum[i][r];
      s += __shfl_xor(s, 1);
      s += __shfl_xor(s, 2);
      s += __shfl_xor(s, 4);
      s += __shfl_xor(s, 8);
      if (fl == 0) scratch[wave*32 + i*16 + fq*4 + r] = s;
    }
  __syncthreads();
  #pragma unroll
  for (int i=0;i<2;i++)
    #pragma unroll
    for (int r=0;r<4;r++){
      int row = i*16 + fq*4 + r;
      inv[i][r] = 1.0f / (scratch[row] + scratch[32+row] + scratch[64+row] + scratch[96+row]);
    }
  __syncthreads();   // scratch done; safe to overwrite Ps with P

  // ---- write unnormalized P (fp16) to LDS in MFMA-A layout ----
  #pragma unroll
  for (int i=0;i<2;i++)
    #pragma unroll
    for (int j=0;j<16;j++){
      int kcol = wave*256 + j*16 + fl;
      short* pp = Ps + (kcol>>3)*256 + (kcol&7);
      #pragma unroll
      for (int r=0;r<4;r++)
        pp[(i*16 + fq*4 + r)*8] = f2hs(accs[i][j][r]);
    }
  __syncthreads();

  // ---- phase 2: ctx = P @ V, wave w owns e-cols [w*192, w*192+192) ----
  f32x4 acco[2][12];
  #pragma unroll
  for (int i=0;i<2;i++)
    #pragma unroll
    for (int j=0;j<12;j++) acco[i][j] = vz;

  for (int kk=0; kk<32; kk++){
    f16x8 ap[2];
    int kc = kk*4 + fq;
    #pragma unroll
    for (int i=0;i<2;i++)
      ap[i] = *(const f16x8*)(Ps + (kc*32 + i*16 + fl)*8);
    #pragma unroll
    for (int j=0;j<12;j++){
      f16x8 bv_ = *(const f16x8*)(Vp + (long)(wave*192 + j*16 + fl)*1024 + kk*32 + fq*8);
      #pragma unroll
      for (int i=0;i<2;i++) acco[i][j] = mfma16(ap[i], bv_, acco[i][j]);
    }
  }

  // ---- normalize, relu, store multi[b*1024+q][h*768+e] ----
  short* mp = multi + (long)(b*1024 + q0)*2304 + h*768;
  #pragma unroll
  for (int j=0;j<12;j++){
    int e = wave*192 + j*16 + fl;
    #pragma unroll
    for (int i=0;i<2;i++){
      int rowb = i*16 + fq*4;
      #pragma unroll
      for (int r=0;r<4;r++){
        float v = fmaxf(acco[i][j][r] * inv[i][r], 0.f);
        mp[(long)(rowb+r)*2304 + e] = f2hs(v);
      }
    }
  }
}

// ---------------- final projection: relu(multi)[8192,2304] @ Wp + bp -> fp32 out ----------------
__global__ __launch_bounds__(256,2) void gemm_out_kernel(
    const short* __restrict__ A, const short* __restrict__ Bt,
    const float* __restrict__ bias, float* __restrict__ out)
{
  __shared__ short As[128*32];
  __shared__ short Bs[128*32];
  const int m0 = blockIdx.x*128, n0 = blockIdx.y*128;
  const int tid = threadIdx.x, wave = tid>>6, lane = tid&63;
  const int wm = wave>>1, wn = wave&1;
  const int fl = lane&15, fq = lane>>4;

  f32x4 vz = {0.f,0.f,0.f,0.f};
  f32x4 acc[4][4];
  #pragma unroll
  for (int i=0;i<4;i++)
    #pragma unroll
    for (int j=0;j<4;j++) acc[i][j] = vz;

  gemm_tile(A, Bt, 2304, m0, n0, As, Bs, acc);

  #pragma unroll
  for (int j=0;j<4;j++){
    int col = n0 + wn*64 + j*16 + fl;
    float bb = bias[col];
    #pragma unroll
    for (int i=0;i<4;i++){
      int row = m0 + wm*64 + i*16 + fq*4;
      #pragma unroll
      for (int r=0;r<4;r++)
        out[(long)(row+r)*768 + col] = acc[i][j][r] + bb;
    }
  }
}

extern "C" void kernel_launch(void* const* d_in, const int* in_sizes, int n_in,
                              void* d_out, int out_size, void* d_ws, size_t ws_size,
                              hipStream_t stream)
{
  const float* t1 = (const float*)d_in[0];
  const float* t2 = (const float*)d_in[1];
  const float* Wq = (const float*)d_in[2];
  const float* bq = (const float*)d_in[3];
  const float* Wk = (const float*)d_in[4];
  const float* bk = (const float*)d_in[5];
  const float* Wv = (const float*)d_in[6];
  const float* bv = (const float*)d_in[7];
  const float* Wp = (const float*)d_in[8];
  const float* bp = (const float*)d_in[9];
  float* out = (float*)d_out;

  char* ws = (char*)d_ws;
  size_t off = 0;
  auto carve = [&](size_t bytes){ void* p = ws + off; off += (bytes + 255) & ~(size_t)255; return p; };
  short* t1b = (short*)carve(8L*1024*768*2);
  short* t2b = (short*)carve(8L*1024*768*2);
  short* WqT = (short*)carve(3L*768*768*2);
  short* WkT = (short*)carve(3L*768*768*2);
  short* WvT = (short*)carve(3L*768*768*2);
  short* WpT = (short*)carve(768L*2304*2);
  short* Qb  = (short*)carve(3L*8192*768*2);
  short* Kb  = (short*)carve(3L*8192*768*2);
  short* Vtb = (short*)carve(3L*8*768*1024*2);    // [h][b][e][lk]
  short* multib = (short*)carve(8192L*2304*2);     // ~190 MB total

  cvt_f16_kernel<<<6144, 256, 0, stream>>>(t1, t1b, 1572864);
  cvt_f16_kernel<<<6144, 256, 0, stream>>>(t2, t2b, 1572864);
  transpose_cvt_kernel<<<dim3(24,24,3), dim3(32,8), 0, stream>>>(Wq, WqT, 768, 768);
  transpose_cvt_kernel<<<dim3(24,24,3), dim3(32,8), 0, stream>>>(Wk, WkT, 768, 768);
  transpose_cvt_kernel<<<dim3(24,24,3), dim3(32,8), 0, stream>>>(Wv, WvT, 768, 768);
  transpose_cvt_kernel<<<dim3(24,72,1), dim3(32,8), 0, stream>>>(Wp, WpT, 2304, 768);
  gemm_qkv_kernel<<<dim3(64,6,9), 256, 0, stream>>>(t1b,t2b,WqT,WkT,WvT,bq,bk,bv,Qb,Kb,Vtb);
  attn_kernel<<<dim3(32,8,3), 256, 0, stream>>>(Qb, Kb, Vtb, multib);
  gemm_out_kernel<<<dim3(64,6,1), 256, 0, stream>>>(multib, WpT, bp, out);
}

// Round 3
// 608.054 us; speedup vs baseline: 1.0010x; 1.0010x over previous
//
#include <hip/hip_runtime.h>
#include <hip/hip_bf16.h>

// CrossAttention: 3 heads, B=8, LQ=LK=1024, H=768.
// Pipeline: cvt -> transpose weights -> QKV gemms (fp16 MFMA) -> fused attention -> out gemm.
// fp16 internally (R1: absmax 4.1e-3 vs 2.39e-2 threshold).
// R2: attn restructured for latency hiding: 512-thread blocks (4 waves/SIMD vs 2) +
//     XCD-swizzled flat grid so each (h,b)'s K/V (3MB) lives in one XCD's 4MB L2.

typedef _Float16 f16;
typedef __attribute__((ext_vector_type(8))) _Float16 f16x8;
typedef __attribute__((ext_vector_type(4))) float f32x4;
typedef __attribute__((ext_vector_type(4))) short s16x4;

#define DI __device__ __forceinline__

DI short f2hs(float f){
  f16 h = (f16)f;                       // RNE
  return __builtin_bit_cast(short, h);
}

DI f32x4 mfma16(f16x8 a, f16x8 b, f32x4 c){
  return __builtin_amdgcn_mfma_f32_16x16x32_f16(a, b, c, 0, 0, 0);
}

#define GLL16(gp, lp) __builtin_amdgcn_global_load_lds( \
    (const __attribute__((address_space(1))) unsigned int*)(gp), \
    (__attribute__((address_space(3))) unsigned int*)(lp), 16, 0, 0)

// ---------------- elementwise f32 -> fp16 ----------------
__global__ void cvt_f16_kernel(const float* __restrict__ in, short* __restrict__ out, int n4){
  int i = blockIdx.x * blockDim.x + threadIdx.x;
  if (i >= n4) return;
  f32x4 v = ((const f32x4*)in)[i];
  s16x4 o;
  o[0]=f2hs(v[0]); o[1]=f2hs(v[1]); o[2]=f2hs(v[2]); o[3]=f2hs(v[3]);
  ((s16x4*)out)[i] = o;
}

// ---------------- transpose + convert: fp32 [R][C] -> fp16 [C][R] ----------------
__global__ void transpose_cvt_kernel(const float* __restrict__ in, short* __restrict__ out, int R, int C){
  __shared__ float tile[32][33];
  long zoff = (long)blockIdx.z * R * C;
  in += zoff; out += zoff;
  int c0 = blockIdx.x * 32, r0 = blockIdx.y * 32;
  int tx = threadIdx.x, ty = threadIdx.y;
  #pragma unroll
  for (int k=0;k<4;k++)
    tile[ty + k*8][tx] = in[(long)(r0 + ty + k*8) * C + c0 + tx];
  __syncthreads();
  #pragma unroll
  for (int k=0;k<4;k++)
    out[(long)(c0 + ty + k*8) * R + r0 + tx] = f2hs(tile[tx][ty + k*8]);
}

// ---------------- shared 128x128 GEMM core (A [M,K] f16, Bt [N,K] f16) ----------------
DI void gemm_tile(const short* __restrict__ A, const short* __restrict__ Bt, int K,
                  int m0, int n0, short* As, short* Bs, f32x4 (&acc)[4][4])
{
  const int tid = threadIdx.x, wave = tid>>6, lane = tid&63;
  const int wm = wave>>1, wn = wave&1;
  const int fl = lane&15, fq = lane>>4;
  const int srow = lane>>2, scol = (lane&3)*8;
  for (int kk=0; kk<K; kk+=32){
    __syncthreads();
    #pragma unroll
    for (int r=0;r<2;r++){
      const int rb = r*64 + wave*16;
      GLL16(A  + (long)(m0+rb+srow)*K + kk + scol, As + rb*32);
      GLL16(Bt + (long)(n0+rb+srow)*K + kk + scol, Bs + rb*32);
    }
    __syncthreads();
    f16x8 a[4];
    #pragma unroll
    for (int i=0;i<4;i++) a[i] = *(const f16x8*)(As + (wm*64+i*16+fl)*32 + fq*8);
    #pragma unroll
    for (int j=0;j<4;j++){
      f16x8 b = *(const f16x8*)(Bs + (wn*64+j*16+fl)*32 + fq*8);
      #pragma unroll
      for (int i=0;i<4;i++) acc[i][j] = mfma16(a[i], b, acc[i][j]);
    }
  }
}

// ---------------- QKV projection: z = which*3 + h; V stored transposed ----------------
__global__ __launch_bounds__(256,2) void gemm_qkv_kernel(
    const short* __restrict__ t1b, const short* __restrict__ t2b,
    const short* __restrict__ WqT, const short* __restrict__ WkT, const short* __restrict__ WvT,
    const float* __restrict__ bq, const float* __restrict__ bk, const float* __restrict__ bv,
    short* __restrict__ Qb, short* __restrict__ Kb, short* __restrict__ Vtb)
{
  __shared__ short As[128*32];
  __shared__ short Bs[128*32];
  const int z = blockIdx.z;
  const int h = z % 3, which = z / 3;
  const short* A  = (which==0) ? t1b : t2b;
  const short* Bt = ((which==0)?WqT:(which==1)?WkT:WvT) + h*768*768;
  const float* bias = ((which==0)?bq:(which==1)?bk:bv) + h*768;
  const int m0 = blockIdx.x*128, n0 = blockIdx.y*128;
  const int tid = threadIdx.x, wave = tid>>6, lane = tid&63;
  const int wm = wave>>1, wn = wave&1;
  const int fl = lane&15, fq = lane>>4;

  f32x4 vz = {0.f,0.f,0.f,0.f};
  f32x4 acc[4][4];
  #pragma unroll
  for (int i=0;i<4;i++)
    #pragma unroll
    for (int j=0;j<4;j++) acc[i][j] = vz;

  gemm_tile(A, Bt, 768, m0, n0, As, Bs, acc);

  if (which < 2){
    short* outp = (which==0 ? Qb : Kb) + (long)h*8192*768;
    #pragma unroll
    for (int j=0;j<4;j++){
      int col = n0 + wn*64 + j*16 + fl;
      float bb = bias[col];
      #pragma unroll
      for (int i=0;i<4;i++){
        int row = m0 + wm*64 + i*16 + fq*4;
        #pragma unroll
        for (int r=0;r<4;r++)
          outp[(long)(row+r)*768 + col] = f2hs(acc[i][j][r] + bb);
      }
    }
  } else {
    const int bidx = m0 >> 10;       // 128-row block never crosses a batch boundary
    const int lk0  = m0 & 1023;
    short* outp = Vtb + (long)(h*8 + bidx)*768*1024;
    #pragma unroll
    for (int j=0;j<4;j++){
      int e = n0 + wn*64 + j*16 + fl;
      float bb = bias[e];
      #pragma unroll
      for (int i=0;i<4;i++){
        int lk = lk0 + wm*64 + i*16 + fq*4;
        s16x4 pack;
        #pragma unroll
        for (int r=0;r<4;r++) pack[r] = f2hs(acc[i][j][r] + bb);
        *(s16x4*)(outp + (long)e*1024 + lk) = pack;
      }
    }
  }
}

// ---------------- fused attention: scores + softmax + PV + relu ----------------
// Flat grid of 768 blocks, 512 threads (8 waves). 32 Q-rows per block.
// XCD swizzle: assuming wg->XCD is id%8, all 32 qtiles of one (h,b) land on one XCD
// so its K/V (3MB) stays resident in that XCD's 4MB L2.
__global__ __launch_bounds__(512,4) void attn_kernel(
    const short* __restrict__ Qb, const short* __restrict__ Kb,
    const short* __restrict__ Vtb, short* __restrict__ multi)
{
  __shared__ short Ps[32768];      // 64KB: P in A-frag layout [kc=k/8][m=32][8]
  __shared__ float scratch[256];   // cross-wave softmax reductions
  const int f = blockIdx.x;
  const int xcd = f & 7, jj = f >> 3;
  const int hb = xcd*3 + (jj >> 5);
  const int q0 = (jj & 31) * 32;
  const int h = hb >> 3, b = hb & 7;
  const int tid = threadIdx.x, wave = tid>>6, lane = tid&63;
  const int fl = lane&15, fq = lane>>4;
  const long qkbase = ((long)h*8192 + b*1024) * 768;
  const short* Qp = Qb + qkbase + (long)q0*768;
  const short* Kp = Kb + qkbase;
  const short* Vp = Vtb + (long)(h*8+b)*768*1024;

  // ---- phase 1: S[32][1024], wave w owns cols [w*128, w*128+128) ----
  f32x4 vz = {0.f,0.f,0.f,0.f};
  f32x4 accs[2][8];
  #pragma unroll
  for (int i=0;i<2;i++)
    #pragma unroll
    for (int j=0;j<8;j++) accs[i][j] = vz;

  for (int kk=0; kk<768; kk+=32){
    f16x8 aq[2];
    #pragma unroll
    for (int i=0;i<2;i++)
      aq[i] = *(const f16x8*)(Qp + (long)(i*16+fl)*768 + kk + fq*8);
    #pragma unroll
    for (int j=0;j<8;j++){
      f16x8 bk_ = *(const f16x8*)(Kp + (long)(wave*128 + j*16 + fl)*768 + kk + fq*8);
      #pragma unroll
      for (int i=0;i<2;i++) accs[i][j] = mfma16(aq[i], bk_, accs[i][j]);
    }
  }

  // ---- softmax (fp32), cross-wave reductions through scratch ----
  float gmax[2][4], inv[2][4];
  #pragma unroll
  for (int i=0;i<2;i++)
    #pragma unroll
    for (int r=0;r<4;r++){
      float m = accs[i][0][r];
      #pragma unroll
      for (int j=1;j<8;j++) m = fmaxf(m, accs[i][j][r]);
      m = fmaxf(m, __shfl_xor(m, 1));
      m = fmaxf(m, __shfl_xor(m, 2));
      m = fmaxf(m, __shfl_xor(m, 4));
      m = fmaxf(m, __shfl_xor(m, 8));
      if (fl == 0) scratch[wave*32 + i*16 + fq*4 + r] = m;
    }
  __syncthreads();
  #pragma unroll
  for (int i=0;i<2;i++)
    #pragma unroll
    for (int r=0;r<4;r++){
      int row = i*16 + fq*4 + r;
      float m = scratch[row];
      #pragma unroll
      for (int w=1;w<8;w++) m = fmaxf(m, scratch[w*32 + row]);
      gmax[i][r] = m;
    }
  __syncthreads();   // scratch reads done before reuse for sums

  float rsum[2][4] = {};
  #pragma unroll
  for (int i=0;i<2;i++)
    #pragma unroll
    for (int j=0;j<8;j++)
      #pragma unroll
      for (int r=0;r<4;r++){
        float p = __expf(accs[i][j][r] - gmax[i][r]);
        accs[i][j][r] = p;
        rsum[i][r] += p;
      }
  #pragma unroll
  for (int i=0;i<2;i++)
    #pragma unroll
    for (int r=0;r<4;r++){
      float s = rsum[i][r];
      s += __shfl_xor(s, 1);
      s += __shfl_xor(s, 2);
      s += __shfl_xor(s, 4);
      s += __shfl_xor(s, 8);
      if (fl == 0) scratch[wave*32 + i*16 + fq*4 + r] = s;
    }

  // ---- write unnormalized P (fp16) to LDS in MFMA-A layout ----
  #pragma unroll
  for (int i=0;i<2;i++)
    #pragma unroll
    for (int j=0;j<8;j++){
      int kcol = wave*128 + j*16 + fl;
      short* pp = Ps + (kcol>>3)*256 + (kcol&7);
      #pragma unroll
      for (int r=0;r<4;r++)
        pp[(i*16 + fq*4 + r)*8] = f2hs(accs[i][j][r]);
    }
  __syncthreads();   // P writes + sum writes both done

  #pragma unroll
  for (int i=0;i<2;i++)
    #pragma unroll
    for (int r=0;r<4;r++){
      int row = i*16 + fq*4 + r;
      float s = scratch[row];
      #pragma unroll
      for (int w=1;w<8;w++) s += scratch[w*32 + row];
      inv[i][r] = 1.0f / s;
    }

  // ---- phase 2: ctx = P @ V, wave w owns e-cols [w*96, w*96+96) ----
  f32x4 acco[2][6];
  #pragma unroll
  for (int i=0;i<2;i++)
    #pragma unroll
    for (int j=0;j<6;j++) acco[i][j] = vz;

  for (int kk=0; kk<32; kk++){
    f16x8 ap[2];
    int kc = kk*4 + fq;
    #pragma unroll
    for (int i=0;i<2;i++)
      ap[i] = *(const f16x8*)(Ps + (kc*32 + i*16 + fl)*8);
    #pragma unroll
    for (int j=0;j<6;j++){
      f16x8 bv_ = *(const f16x8*)(Vp + (long)(wave*96 + j*16 + fl)*1024 + kk*32 + fq*8);
      #pragma unroll
      for (int i=0;i<2;i++) acco[i][j] = mfma16(ap[i], bv_, acco[i][j]);
    }
  }

  // ---- normalize, relu, store multi[b*1024+q][h*768+e] ----
  short* mp = multi + (long)(b*1024 + q0)*2304 + h*768;
  #pragma unroll
  for (int j=0;j<6;j++){
    int e = wave*96 + j*16 + fl;
    #pragma unroll
    for (int i=0;i<2;i++){
      int rowb = i*16 + fq*4;
      #pragma unroll
      for (int r=0;r<4;r++){
        float v = fmaxf(acco[i][j][r] * inv[i][r], 0.f);
        mp[(long)(rowb+r)*2304 + e] = f2hs(v);
      }
    }
  }
}

// ---------------- final projection: relu(multi)[8192,2304] @ Wp + bp -> fp32 out ----------------
__global__ __launch_bounds__(256,2) void gemm_out_kernel(
    const short* __restrict__ A, const short* __restrict__ Bt,
    const float* __restrict__ bias, float* __restrict__ out)
{
  __shared__ short As[128*32];
  __shared__ short Bs[128*32];
  const int m0 = blockIdx.x*128, n0 = blockIdx.y*128;
  const int tid = threadIdx.x, wave = tid>>6, lane = tid&63;
  const int wm = wave>>1, wn = wave&1;
  const int fl = lane&15, fq = lane>>4;

  f32x4 vz = {0.f,0.f,0.f,0.f};
  f32x4 acc[4][4];
  #pragma unroll
  for (int i=0;i<4;i++)
    #pragma unroll
    for (int j=0;j<4;j++) acc[i][j] = vz;

  gemm_tile(A, Bt, 2304, m0, n0, As, Bs, acc);

  #pragma unroll
  for (int j=0;j<4;j++){
    int col = n0 + wn*64 + j*16 + fl;
    float bb = bias[col];
    #pragma unroll
    for (int i=0;i<4;i++){
      int row = m0 + wm*64 + i*16 + fq*4;
      #pragma unroll
      for (int r=0;r<4;r++)
        out[(long)(row+r)*768 + col] = acc[i][j][r] + bb;
    }
  }
}

extern "C" void kernel_launch(void* const* d_in, const int* in_sizes, int n_in,
                              void* d_out, int out_size, void* d_ws, size_t ws_size,
                              hipStream_t stream)
{
  const float* t1 = (const float*)d_in[0];
  const float* t2 = (const float*)d_in[1];
  const float* Wq = (const float*)d_in[2];
  const float* bq = (const float*)d_in[3];
  const float* Wk = (const float*)d_in[4];
  const float* bk = (const float*)d_in[5];
  const float* Wv = (const float*)d_in[6];
  const float* bv = (const float*)d_in[7];
  const float* Wp = (const float*)d_in[8];
  const float* bp = (const float*)d_in[9];
  float* out = (float*)d_out;

  char* ws = (char*)d_ws;
  size_t off = 0;
  auto carve = [&](size_t bytes){ void* p = ws + off; off += (bytes + 255) & ~(size_t)255; return p; };
  short* t1b = (short*)carve(8L*1024*768*2);
  short* t2b = (short*)carve(8L*1024*768*2);
  short* WqT = (short*)carve(3L*768*768*2);
  short* WkT = (short*)carve(3L*768*768*2);
  short* WvT = (short*)carve(3L*768*768*2);
  short* WpT = (short*)carve(768L*2304*2);
  short* Qb  = (short*)carve(3L*8192*768*2);
  short* Kb  = (short*)carve(3L*8192*768*2);
  short* Vtb = (short*)carve(3L*8*768*1024*2);    // [h][b][e][lk]
  short* multib = (short*)carve(8192L*2304*2);     // ~190 MB total

  cvt_f16_kernel<<<6144, 256, 0, stream>>>(t1, t1b, 1572864);
  cvt_f16_kernel<<<6144, 256, 0, stream>>>(t2, t2b, 1572864);
  transpose_cvt_kernel<<<dim3(24,24,3), dim3(32,8), 0, stream>>>(Wq, WqT, 768, 768);
  transpose_cvt_kernel<<<dim3(24,24,3), dim3(32,8), 0, stream>>>(Wk, WkT, 768, 768);
  transpose_cvt_kernel<<<dim3(24,24,3), dim3(32,8), 0, stream>>>(Wv, WvT, 768, 768);
  transpose_cvt_kernel<<<dim3(24,72,1), dim3(32,8), 0, stream>>>(Wp, WpT, 2304, 768);
  gemm_qkv_kernel<<<dim3(64,6,9), 256, 0, stream>>>(t1b,t2b,WqT,WkT,WvT,bq,bk,bv,Qb,Kb,Vtb);
  attn_kernel<<<768, 512, 0, stream>>>(Qb, Kb, Vtb, multib);
  gemm_out_kernel<<<dim3(64,6,1), 256, 0, stream>>>(multib, WpT, bp, out);
}

// Round 4
// 462.356 us; speedup vs baseline: 1.3164x; 1.3151x over previous
//
#include <hip/hip_runtime.h>
#include <hip/hip_bf16.h>

// CrossAttention: 3 heads, B=8, LQ=LK=1024, H=768.
// R3: attention as 3 stages, both matmuls in the m97 128x128 LDS-staged GEMM structure:
//   qk_exp (S-tile GEMM + tile-local exp) -> scale_p (global softmax rescale) -> pv (GEMM + relu).
// Rationale (R2 post-mortem): 32-row q-tiles streamed 9MB/CU of K/V through L1 via
// per-wave fragment loads -> TA-throughput-bound at 9.5% MfmaUtil. 128-row tiles with
// LDS-shared K cut per-CU L1 bytes ~8x and reuse the proven 30-37%-MfmaUtil GEMM loop.

typedef _Float16 f16;
typedef __attribute__((ext_vector_type(8))) _Float16 f16x8;
typedef __attribute__((ext_vector_type(4))) float f32x4;
typedef __attribute__((ext_vector_type(4))) short s16x4;
typedef __attribute__((ext_vector_type(8))) short s16x8;

#define DI __device__ __forceinline__

DI short f2hs(float f){
  f16 h = (f16)f;                       // RNE
  return __builtin_bit_cast(short, h);
}
DI float hs2f(short s){
  return (float)__builtin_bit_cast(f16, s);
}

DI f32x4 mfma16(f16x8 a, f16x8 b, f32x4 c){
  return __builtin_amdgcn_mfma_f32_16x16x32_f16(a, b, c, 0, 0, 0);
}

#define GLL16(gp, lp) __builtin_amdgcn_global_load_lds( \
    (const __attribute__((address_space(1))) unsigned int*)(gp), \
    (__attribute__((address_space(3))) unsigned int*)(lp), 16, 0, 0)

// ---------------- elementwise f32 -> fp16 ----------------
__global__ void cvt_f16_kernel(const float* __restrict__ in, short* __restrict__ out, int n4){
  int i = blockIdx.x * blockDim.x + threadIdx.x;
  if (i >= n4) return;
  f32x4 v = ((const f32x4*)in)[i];
  s16x4 o;
  o[0]=f2hs(v[0]); o[1]=f2hs(v[1]); o[2]=f2hs(v[2]); o[3]=f2hs(v[3]);
  ((s16x4*)out)[i] = o;
}

// ---------------- transpose + convert: fp32 [R][C] -> fp16 [C][R] ----------------
__global__ void transpose_cvt_kernel(const float* __restrict__ in, short* __restrict__ out, int R, int C){
  __shared__ float tile[32][33];
  long zoff = (long)blockIdx.z * R * C;
  in += zoff; out += zoff;
  int c0 = blockIdx.x * 32, r0 = blockIdx.y * 32;
  int tx = threadIdx.x, ty = threadIdx.y;
  #pragma unroll
  for (int k=0;k<4;k++)
    tile[ty + k*8][tx] = in[(long)(r0 + ty + k*8) * C + c0 + tx];
  __syncthreads();
  #pragma unroll
  for (int k=0;k<4;k++)
    out[(long)(c0 + ty + k*8) * R + r0 + tx] = f2hs(tile[tx][ty + k*8]);
}

// ---------------- shared 128x128 GEMM core (A [M,K] f16, Bt [N,K] f16) ----------------
DI void gemm_tile(const short* __restrict__ A, const short* __restrict__ Bt, int K,
                  int m0, int n0, short* As, short* Bs, f32x4 (&acc)[4][4])
{
  const int tid = threadIdx.x, wave = tid>>6, lane = tid&63;
  const int wm = wave>>1, wn = wave&1;
  const int fl = lane&15, fq = lane>>4;
  const int srow = lane>>2, scol = (lane&3)*8;
  for (int kk=0; kk<K; kk+=32){
    __syncthreads();
    #pragma unroll
    for (int r=0;r<2;r++){
      const int rb = r*64 + wave*16;
      GLL16(A  + (long)(m0+rb+srow)*K + kk + scol, As + rb*32);
      GLL16(Bt + (long)(n0+rb+srow)*K + kk + scol, Bs + rb*32);
    }
    __syncthreads();
    f16x8 a[4];
    #pragma unroll
    for (int i=0;i<4;i++) a[i] = *(const f16x8*)(As + (wm*64+i*16+fl)*32 + fq*8);
    #pragma unroll
    for (int j=0;j<4;j++){
      f16x8 b = *(const f16x8*)(Bs + (wn*64+j*16+fl)*32 + fq*8);
      #pragma unroll
      for (int i=0;i<4;i++) acc[i][j] = mfma16(a[i], b, acc[i][j]);
    }
  }
}

// ---------------- QKV projection: z = which*3 + h; V stored transposed ----------------
__global__ __launch_bounds__(256,2) void gemm_qkv_kernel(
    const short* __restrict__ t1b, const short* __restrict__ t2b,
    const short* __restrict__ WqT, const short* __restrict__ WkT, const short* __restrict__ WvT,
    const float* __restrict__ bq, const float* __restrict__ bk, const float* __restrict__ bv,
    short* __restrict__ Qb, short* __restrict__ Kb, short* __restrict__ Vtb)
{
  __shared__ short As[128*32];
  __shared__ short Bs[128*32];
  const int z = blockIdx.z;
  const int h = z % 3, which = z / 3;
  const short* A  = (which==0) ? t1b : t2b;
  const short* Bt = ((which==0)?WqT:(which==1)?WkT:WvT) + h*768*768;
  const float* bias = ((which==0)?bq:(which==1)?bk:bv) + h*768;
  const int m0 = blockIdx.x*128, n0 = blockIdx.y*128;
  const int tid = threadIdx.x, wave = tid>>6, lane = tid&63;
  const int wm = wave>>1, wn = wave&1;
  const int fl = lane&15, fq = lane>>4;

  f32x4 vz = {0.f,0.f,0.f,0.f};
  f32x4 acc[4][4];
  #pragma unroll
  for (int i=0;i<4;i++)
    #pragma unroll
    for (int j=0;j<4;j++) acc[i][j] = vz;

  gemm_tile(A, Bt, 768, m0, n0, As, Bs, acc);

  if (which < 2){
    short* outp = (which==0 ? Qb : Kb) + (long)h*8192*768;
    #pragma unroll
    for (int j=0;j<4;j++){
      int col = n0 + wn*64 + j*16 + fl;
      float bb = bias[col];
      #pragma unroll
      for (int i=0;i<4;i++){
        int row = m0 + wm*64 + i*16 + fq*4;
        #pragma unroll
        for (int r=0;r<4;r++)
          outp[(long)(row+r)*768 + col] = f2hs(acc[i][j][r] + bb);
      }
    }
  } else {
    const int bidx = m0 >> 10;       // 128-row block never crosses a batch boundary
    const int lk0  = m0 & 1023;
    short* outp = Vtb + (long)(h*8 + bidx)*768*1024;
    #pragma unroll
    for (int j=0;j<4;j++){
      int e = n0 + wn*64 + j*16 + fl;
      float bb = bias[e];
      #pragma unroll
      for (int i=0;i<4;i++){
        int lk = lk0 + wm*64 + i*16 + fq*4;
        s16x4 pack;
        #pragma unroll
        for (int r=0;r<4;r++) pack[r] = f2hs(acc[i][j][r] + bb);
        *(s16x4*)(outp + (long)e*1024 + lk) = pack;
      }
    }
  }
}

// ---------------- attention stage 1: S-tile GEMM + tile-local exp ----------------
// grid (8 qt, 8 ct, 24 hb), 256 thr. Writes P_u = exp(s - m_t) fp16, and m_t, l_t per (row, ctile).
__global__ __launch_bounds__(256,2) void qk_exp_kernel(
    const short* __restrict__ Qb, const short* __restrict__ Kb,
    short* __restrict__ P, float* __restrict__ Mx, float* __restrict__ Lx)
{
  __shared__ short As[128*32];
  __shared__ short Bs[128*32];
  __shared__ float red0[2][2][64];   // [wn][wm][row64] tile-local max
  __shared__ float red1[2][2][64];   // [wn][wm][row64] tile-local sum
  const int qt = blockIdx.x, ct = blockIdx.y, hb = blockIdx.z;
  const int h = hb >> 3, b = hb & 7;
  const int tid = threadIdx.x, wave = tid>>6, lane = tid&63;
  const int wm = wave>>1, wn = wave&1;
  const int fl = lane&15, fq = lane>>4;
  const short* Abase = Qb + ((long)h*8192 + b*1024)*768;
  const short* Bbase = Kb + ((long)h*8192 + b*1024)*768;

  f32x4 vz = {0.f,0.f,0.f,0.f};
  f32x4 acc[4][4];
  #pragma unroll
  for (int i=0;i<4;i++)
    #pragma unroll
    for (int j=0;j<4;j++) acc[i][j] = vz;

  gemm_tile(Abase, Bbase, 768, qt*128, ct*128, As, Bs, acc);

  // tile-local row max over this wave's 64 cols, then across wn pair via LDS
  float mt[4][4];
  #pragma unroll
  for (int i=0;i<4;i++)
    #pragma unroll
    for (int r=0;r<4;r++){
      float m = acc[i][0][r];
      #pragma unroll
      for (int j=1;j<4;j++) m = fmaxf(m, acc[i][j][r]);
      m = fmaxf(m, __shfl_xor(m, 1));
      m = fmaxf(m, __shfl_xor(m, 2));
      m = fmaxf(m, __shfl_xor(m, 4));
      m = fmaxf(m, __shfl_xor(m, 8));
      mt[i][r] = m;
      if (fl == 0) red0[wn][wm][i*16 + fq*4 + r] = m;
    }
  __syncthreads();
  #pragma unroll
  for (int i=0;i<4;i++)
    #pragma unroll
    for (int r=0;r<4;r++)
      mt[i][r] = fmaxf(red0[0][wm][i*16 + fq*4 + r], red0[1][wm][i*16 + fq*4 + r]);

  // exp + tile-local sums
  float lt[4][4];
  #pragma unroll
  for (int i=0;i<4;i++)
    #pragma unroll
    for (int r=0;r<4;r++){
      float s = 0.f;
      #pragma unroll
      for (int j=0;j<4;j++){
        float p = __expf(acc[i][j][r] - mt[i][r]);
        acc[i][j][r] = p;
        s += p;
      }
      s += __shfl_xor(s, 1);
      s += __shfl_xor(s, 2);
      s += __shfl_xor(s, 4);
      s += __shfl_xor(s, 8);
      if (fl == 0) red1[wn][wm][i*16 + fq*4 + r] = s;
    }
  __syncthreads();
  #pragma unroll
  for (int i=0;i<4;i++)
    #pragma unroll
    for (int r=0;r<4;r++)
      lt[i][r] = red1[0][wm][i*16 + fq*4 + r] + red1[1][wm][i*16 + fq*4 + r];

  // store P_u (fp16) and per-(row, ctile) aux
  #pragma unroll
  for (int j=0;j<4;j++){
    int c = ct*128 + wn*64 + j*16 + fl;
    #pragma unroll
    for (int i=0;i<4;i++){
      int q = qt*128 + wm*64 + i*16 + fq*4;
      #pragma unroll
      for (int r=0;r<4;r++)
        P[((long)hb*1024 + q + r)*1024 + c] = f2hs(acc[i][j][r]);
    }
  }
  if (fl == 0 && wn == 0){
    long aux = ((long)(hb*8 + ct))*1024 + qt*128;
    #pragma unroll
    for (int i=0;i<4;i++)
      #pragma unroll
      for (int r=0;r<4;r++){
        int row = wm*64 + i*16 + fq*4 + r;
        Mx[aux + row] = mt[i][r];
        Lx[aux + row] = lt[i][r];
      }
  }
}

// ---------------- attention stage 2: global softmax rescale of P ----------------
// One wave per q-row; 8 waves/block. P <- P_u * exp(m_t - m_g) / l_g.
__global__ __launch_bounds__(512,4) void scale_p_kernel(
    short* __restrict__ P, const float* __restrict__ Mx, const float* __restrict__ Lx)
{
  const int tid = threadIdx.x, wave = tid>>6, lane = tid&63;
  const int R = blockIdx.x*8 + wave;           // [0, 24576)
  const int hb = R >> 10, q = R & 1023;
  float mt[8], ltv[8];
  #pragma unroll
  for (int t=0;t<8;t++){
    long a = ((long)(hb*8 + t))*1024 + q;
    mt[t] = Mx[a];
    ltv[t] = Lx[a];
  }
  float mg = mt[0];
  #pragma unroll
  for (int t=1;t<8;t++) mg = fmaxf(mg, mt[t]);
  float lg = 0.f;
  #pragma unroll
  for (int t=0;t<8;t++) lg += ltv[t] * __expf(mt[t] - mg);
  float inv = 1.0f / lg;
  float sc[8];
  #pragma unroll
  for (int t=0;t<8;t++) sc[t] = __expf(mt[t] - mg) * inv;

  short* row = P + (long)R * 1024;
  #pragma unroll
  for (int it=0; it<2; it++){
    int c0 = it*512 + lane*8;
    float s = sc[c0 >> 7];
    s16x8 v = *(s16x8*)(row + c0);
    #pragma unroll
    for (int e=0;e<8;e++) v[e] = f2hs(hs2f(v[e]) * s);
    *(s16x8*)(row + c0) = v;
  }
}

// ---------------- attention stage 3: ctx = P @ V^T, relu, store multi ----------------
// grid (8 qt, 6 et, 24 hb), 256 thr.
__global__ __launch_bounds__(256,2) void pv_kernel(
    const short* __restrict__ P, const short* __restrict__ Vtb, short* __restrict__ multi)
{
  __shared__ short As[128*32];
  __shared__ short Bs[128*32];
  const int qt = blockIdx.x, et = blockIdx.y, hb = blockIdx.z;
  const int h = hb >> 3, b = hb & 7;
  const int tid = threadIdx.x, wave = tid>>6, lane = tid&63;
  const int wm = wave>>1, wn = wave&1;
  const int fl = lane&15, fq = lane>>4;
  const short* Abase = P + (long)hb*1024*1024;
  const short* Bbase = Vtb + (long)hb*768*1024;

  f32x4 vz = {0.f,0.f,0.f,0.f};
  f32x4 acc[4][4];
  #pragma unroll
  for (int i=0;i<4;i++)
    #pragma unroll
    for (int j=0;j<4;j++) acc[i][j] = vz;

  gemm_tile(Abase, Bbase, 1024, qt*128, et*128, As, Bs, acc);

  short* mp = multi + (long)(b*1024)*2304 + h*768;
  #pragma unroll
  for (int j=0;j<4;j++){
    int e = et*128 + wn*64 + j*16 + fl;
    #pragma unroll
    for (int i=0;i<4;i++){
      int q = qt*128 + wm*64 + i*16 + fq*4;
      #pragma unroll
      for (int r=0;r<4;r++)
        mp[(long)(q+r)*2304 + e] = f2hs(fmaxf(acc[i][j][r], 0.f));
    }
  }
}

// ---------------- final projection: relu(multi)[8192,2304] @ Wp + bp -> fp32 out ----------------
__global__ __launch_bounds__(256,2) void gemm_out_kernel(
    const short* __restrict__ A, const short* __restrict__ Bt,
    const float* __restrict__ bias, float* __restrict__ out)
{
  __shared__ short As[128*32];
  __shared__ short Bs[128*32];
  const int m0 = blockIdx.x*128, n0 = blockIdx.y*128;
  const int tid = threadIdx.x, wave = tid>>6, lane = tid&63;
  const int wm = wave>>1, wn = wave&1;
  const int fl = lane&15, fq = lane>>4;

  f32x4 vz = {0.f,0.f,0.f,0.f};
  f32x4 acc[4][4];
  #pragma unroll
  for (int i=0;i<4;i++)
    #pragma unroll
    for (int j=0;j<4;j++) acc[i][j] = vz;

  gemm_tile(A, Bt, 2304, m0, n0, As, Bs, acc);

  #pragma unroll
  for (int j=0;j<4;j++){
    int col = n0 + wn*64 + j*16 + fl;
    float bb = bias[col];
    #pragma unroll
    for (int i=0;i<4;i++){
      int row = m0 + wm*64 + i*16 + fq*4;
      #pragma unroll
      for (int r=0;r<4;r++)
        out[(long)(row+r)*768 + col] = acc[i][j][r] + bb;
    }
  }
}

extern "C" void kernel_launch(void* const* d_in, const int* in_sizes, int n_in,
                              void* d_out, int out_size, void* d_ws, size_t ws_size,
                              hipStream_t stream)
{
  const float* t1 = (const float*)d_in[0];
  const float* t2 = (const float*)d_in[1];
  const float* Wq = (const float*)d_in[2];
  const float* bq = (const float*)d_in[3];
  const float* Wk = (const float*)d_in[4];
  const float* bk = (const float*)d_in[5];
  const float* Wv = (const float*)d_in[6];
  const float* bv = (const float*)d_in[7];
  const float* Wp = (const float*)d_in[8];
  const float* bp = (const float*)d_in[9];
  float* out = (float*)d_out;

  char* ws = (char*)d_ws;
  size_t off = 0;
  auto carve = [&](size_t bytes){ void* p = ws + off; off += (bytes + 255) & ~(size_t)255; return p; };
  short* t1b = (short*)carve(8L*1024*768*2);
  short* t2b = (short*)carve(8L*1024*768*2);
  short* WqT = (short*)carve(3L*768*768*2);
  short* WkT = (short*)carve(3L*768*768*2);
  short* WvT = (short*)carve(3L*768*768*2);
  short* WpT = (short*)carve(768L*2304*2);
  short* Qb  = (short*)carve(3L*8192*768*2);
  short* Kb  = (short*)carve(3L*8192*768*2);
  short* Vtb = (short*)carve(3L*8*768*1024*2);    // [hb][e][lk]
  short* Pb  = (short*)carve(24L*1024*1024*2);    // [hb][q][c]
  float* Mx  = (float*)carve(24L*8*1024*4);       // [hb*8+ct][q]
  float* Lx  = (float*)carve(24L*8*1024*4);
  short* multib = Qb;   // alias: Qb dead after qk_exp; multi written by pv, read by gemm_out

  cvt_f16_kernel<<<6144, 256, 0, stream>>>(t1, t1b, 1572864);
  cvt_f16_kernel<<<6144, 256, 0, stream>>>(t2, t2b, 1572864);
  transpose_cvt_kernel<<<dim3(24,24,3), dim3(32,8), 0, stream>>>(Wq, WqT, 768, 768);
  transpose_cvt_kernel<<<dim3(24,24,3), dim3(32,8), 0, stream>>>(Wk, WkT, 768, 768);
  transpose_cvt_kernel<<<dim3(24,24,3), dim3(32,8), 0, stream>>>(Wv, WvT, 768, 768);
  transpose_cvt_kernel<<<dim3(24,72,1), dim3(32,8), 0, stream>>>(Wp, WpT, 2304, 768);
  gemm_qkv_kernel<<<dim3(64,6,9), 256, 0, stream>>>(t1b,t2b,WqT,WkT,WvT,bq,bk,bv,Qb,Kb,Vtb);
  qk_exp_kernel<<<dim3(8,8,24), 256, 0, stream>>>(Qb, Kb, Pb, Mx, Lx);
  scale_p_kernel<<<3072, 512, 0, stream>>>(Pb, Mx, Lx);
  pv_kernel<<<dim3(8,6,24), 256, 0, stream>>>(Pb, Vtb, multib);
  gemm_out_kernel<<<dim3(64,6,1), 256, 0, stream>>>(multib, WpT, bp, out);
}

// Round 5
// 443.836 us; speedup vs baseline: 1.3713x; 1.0417x over previous
//
#include <hip/hip_runtime.h>
#include <hip/hip_bf16.h>

// CrossAttention: 3 heads, B=8, LQ=LK=1024, H=768.
// R4: (1) XOR bank-swizzle in the shared 128x128 GEMM tile -> conflict-free ds_read_b128
//     (R3 counter: 1.06e7 conflict cycles = 13% of gemm_qkv). Chunk g of row r is stored
//     at slot g^(r&3); global coalescing unchanged (same 64B per 4-lane group, permuted).
//     (2) scale_p folded into pv: per-ctile factor f=exp(m_t-m_g)/l_g applied to P
//     A-fragments via v_pk_mul_f16 (k-chunks never cross ctile boundaries) -> saves the
//     100MB P round-trip. (3) merged prep launches.

typedef _Float16 f16;
typedef __attribute__((ext_vector_type(8))) _Float16 f16x8;
typedef __attribute__((ext_vector_type(4))) float f32x4;
typedef __attribute__((ext_vector_type(4))) short s16x4;

#define DI __device__ __forceinline__

DI short f2hs(float f){
  f16 h = (f16)f;                       // RNE
  return __builtin_bit_cast(short, h);
}

DI f32x4 mfma16(f16x8 a, f16x8 b, f32x4 c){
  return __builtin_amdgcn_mfma_f32_16x16x32_f16(a, b, c, 0, 0, 0);
}

#define GLL16(gp, lp) __builtin_amdgcn_global_load_lds( \
    (const __attribute__((address_space(1))) unsigned int*)(gp), \
    (__attribute__((address_space(3))) unsigned int*)(lp), 16, 0, 0)

// ---------------- elementwise f32 -> fp16, t1 and t2 in one launch ----------------
__global__ void cvt2_f16_kernel(const float* __restrict__ a, const float* __restrict__ b,
                                short* __restrict__ oa, short* __restrict__ ob, int n4each){
  int i = blockIdx.x * blockDim.x + threadIdx.x;
  const float* in = (i < n4each) ? a : b;
  short* out = (i < n4each) ? oa : ob;
  int j = (i < n4each) ? i : i - n4each;
  f32x4 v = ((const f32x4*)in)[j];
  s16x4 o;
  o[0]=f2hs(v[0]); o[1]=f2hs(v[1]); o[2]=f2hs(v[2]); o[3]=f2hs(v[3]);
  ((s16x4*)out)[j] = o;
}

// ---------------- transpose + convert Wq/Wk/Wv: fp32 [768][768] -> fp16 [768][768]^T ----------------
__global__ void transpose_cvt_qkv_kernel(const float* __restrict__ Wq, const float* __restrict__ Wk,
                                         const float* __restrict__ Wv,
                                         short* __restrict__ WqT, short* __restrict__ WkT,
                                         short* __restrict__ WvT){
  __shared__ float tile[32][33];
  const int t = blockIdx.z / 3, hd = blockIdx.z % 3;
  const float* in = ((t==0)?Wq:(t==1)?Wk:Wv) + (long)hd*768*768;
  short* out = ((t==0)?WqT:(t==1)?WkT:WvT) + (long)hd*768*768;
  int c0 = blockIdx.x * 32, r0 = blockIdx.y * 32;
  int tx = threadIdx.x, ty = threadIdx.y;
  #pragma unroll
  for (int k=0;k<4;k++)
    tile[ty + k*8][tx] = in[(long)(r0 + ty + k*8) * 768 + c0 + tx];
  __syncthreads();
  #pragma unroll
  for (int k=0;k<4;k++)
    out[(long)(c0 + ty + k*8) * 768 + r0 + tx] = f2hs(tile[tx][ty + k*8]);
}

// ---------------- transpose + convert Wp: fp32 [2304][768] -> fp16 [768][2304] ----------------
__global__ void transpose_cvt_kernel(const float* __restrict__ in, short* __restrict__ out, int R, int C){
  __shared__ float tile[32][33];
  int c0 = blockIdx.x * 32, r0 = blockIdx.y * 32;
  int tx = threadIdx.x, ty = threadIdx.y;
  #pragma unroll
  for (int k=0;k<4;k++)
    tile[ty + k*8][tx] = in[(long)(r0 + ty + k*8) * C + c0 + tx];
  __syncthreads();
  #pragma unroll
  for (int k=0;k<4;k++)
    out[(long)(c0 + ty + k*8) * R + r0 + tx] = f2hs(tile[tx][ty + k*8]);
}

// ---------------- shared 128x128 GEMM core, XOR bank-swizzled LDS ----------------
// LDS slot (row, c) holds global k-chunk g = c ^ (row&3); 16B chunks, 64B rows.
DI void gemm_tile(const short* __restrict__ A, const short* __restrict__ Bt, int K,
                  int m0, int n0, short* As, short* Bs, f32x4 (&acc)[4][4])
{
  const int tid = threadIdx.x, wave = tid>>6, lane = tid&63;
  const int wm = wave>>1, wn = wave&1;
  const int fl = lane&15, fq = lane>>4;
  const int srow = lane>>2;
  const int scol = (((lane&3) ^ (srow&3)))*8;     // swizzled global chunk for this lane
  const int aswz = ((fq ^ (fl&3)))*8;             // swizzled read slot offset (shorts)
  for (int kk=0; kk<K; kk+=32){
    __syncthreads();
    #pragma unroll
    for (int r=0;r<2;r++){
      const int rb = r*64 + wave*16;
      GLL16(A  + (long)(m0+rb+srow)*K + kk + scol, As + rb*32);
      GLL16(Bt + (long)(n0+rb+srow)*K + kk + scol, Bs + rb*32);
    }
    __syncthreads();
    f16x8 a[4];
    #pragma unroll
    for (int i=0;i<4;i++) a[i] = *(const f16x8*)(As + (wm*64+i*16+fl)*32 + aswz);
    #pragma unroll
    for (int j=0;j<4;j++){
      f16x8 b = *(const f16x8*)(Bs + (wn*64+j*16+fl)*32 + aswz);
      #pragma unroll
      for (int i=0;i<4;i++) acc[i][j] = mfma16(a[i], b, acc[i][j]);
    }
  }
}

// ---------------- QKV projection: z = which*3 + h; V stored transposed ----------------
__global__ __launch_bounds__(256,2) void gemm_qkv_kernel(
    const short* __restrict__ t1b, const short* __restrict__ t2b,
    const short* __restrict__ WqT, const short* __restrict__ WkT, const short* __restrict__ WvT,
    const float* __restrict__ bq, const float* __restrict__ bk, const float* __restrict__ bv,
    short* __restrict__ Qb, short* __restrict__ Kb, short* __restrict__ Vtb)
{
  __shared__ short As[128*32];
  __shared__ short Bs[128*32];
  const int z = blockIdx.z;
  const int h = z % 3, which = z / 3;
  const short* A  = (which==0) ? t1b : t2b;
  const short* Bt = ((which==0)?WqT:(which==1)?WkT:WvT) + h*768*768;
  const float* bias = ((which==0)?bq:(which==1)?bk:bv) + h*768;
  const int m0 = blockIdx.x*128, n0 = blockIdx.y*128;
  const int tid = threadIdx.x, wave = tid>>6, lane = tid&63;
  const int wm = wave>>1, wn = wave&1;
  const int fl = lane&15, fq = lane>>4;

  f32x4 vz = {0.f,0.f,0.f,0.f};
  f32x4 acc[4][4];
  #pragma unroll
  for (int i=0;i<4;i++)
    #pragma unroll
    for (int j=0;j<4;j++) acc[i][j] = vz;

  gemm_tile(A, Bt, 768, m0, n0, As, Bs, acc);

  if (which < 2){
    short* outp = (which==0 ? Qb : Kb) + (long)h*8192*768;
    #pragma unroll
    for (int j=0;j<4;j++){
      int col = n0 + wn*64 + j*16 + fl;
      float bb = bias[col];
      #pragma unroll
      for (int i=0;i<4;i++){
        int row = m0 + wm*64 + i*16 + fq*4;
        #pragma unroll
        for (int r=0;r<4;r++)
          outp[(long)(row+r)*768 + col] = f2hs(acc[i][j][r] + bb);
      }
    }
  } else {
    const int bidx = m0 >> 10;       // 128-row block never crosses a batch boundary
    const int lk0  = m0 & 1023;
    short* outp = Vtb + (long)(h*8 + bidx)*768*1024;
    #pragma unroll
    for (int j=0;j<4;j++){
      int e = n0 + wn*64 + j*16 + fl;
      float bb = bias[e];
      #pragma unroll
      for (int i=0;i<4;i++){
        int lk = lk0 + wm*64 + i*16 + fq*4;
        s16x4 pack;
        #pragma unroll
        for (int r=0;r<4;r++) pack[r] = f2hs(acc[i][j][r] + bb);
        *(s16x4*)(outp + (long)e*1024 + lk) = pack;
      }
    }
  }
}

// ---------------- attention stage 1: S-tile GEMM + tile-local exp ----------------
// grid (8 qt, 8 ct, 24 hb), 256 thr. Writes P_u = exp(s - m_t) fp16, and m_t, l_t per (row, ctile).
__global__ __launch_bounds__(256,2) void qk_exp_kernel(
    const short* __restrict__ Qb, const short* __restrict__ Kb,
    short* __restrict__ P, float* __restrict__ Mx, float* __restrict__ Lx)
{
  __shared__ short As[128*32];
  __shared__ short Bs[128*32];
  __shared__ float red0[2][2][64];   // [wn][wm][row64] tile-local max
  __shared__ float red1[2][2][64];   // [wn][wm][row64] tile-local sum
  const int qt = blockIdx.x, ct = blockIdx.y, hb = blockIdx.z;
  const int h = hb >> 3, b = hb & 7;
  const int tid = threadIdx.x, wave = tid>>6, lane = tid&63;
  const int wm = wave>>1, wn = wave&1;
  const int fl = lane&15, fq = lane>>4;
  const short* Abase = Qb + ((long)h*8192 + b*1024)*768;
  const short* Bbase = Kb + ((long)h*8192 + b*1024)*768;

  f32x4 vz = {0.f,0.f,0.f,0.f};
  f32x4 acc[4][4];
  #pragma unroll
  for (int i=0;i<4;i++)
    #pragma unroll
    for (int j=0;j<4;j++) acc[i][j] = vz;

  gemm_tile(Abase, Bbase, 768, qt*128, ct*128, As, Bs, acc);

  // tile-local row max over this wave's 64 cols, then across wn pair via LDS
  float mt[4][4];
  #pragma unroll
  for (int i=0;i<4;i++)
    #pragma unroll
    for (int r=0;r<4;r++){
      float m = acc[i][0][r];
      #pragma unroll
      for (int j=1;j<4;j++) m = fmaxf(m, acc[i][j][r]);
      m = fmaxf(m, __shfl_xor(m, 1));
      m = fmaxf(m, __shfl_xor(m, 2));
      m = fmaxf(m, __shfl_xor(m, 4));
      m = fmaxf(m, __shfl_xor(m, 8));
      mt[i][r] = m;
      if (fl == 0) red0[wn][wm][i*16 + fq*4 + r] = m;
    }
  __syncthreads();
  #pragma unroll
  for (int i=0;i<4;i++)
    #pragma unroll
    for (int r=0;r<4;r++)
      mt[i][r] = fmaxf(red0[0][wm][i*16 + fq*4 + r], red0[1][wm][i*16 + fq*4 + r]);

  // exp + tile-local sums
  #pragma unroll
  for (int i=0;i<4;i++)
    #pragma unroll
    for (int r=0;r<4;r++){
      float s = 0.f;
      #pragma unroll
      for (int j=0;j<4;j++){
        float p = __expf(acc[i][j][r] - mt[i][r]);
        acc[i][j][r] = p;
        s += p;
      }
      s += __shfl_xor(s, 1);
      s += __shfl_xor(s, 2);
      s += __shfl_xor(s, 4);
      s += __shfl_xor(s, 8);
      if (fl == 0) red1[wn][wm][i*16 + fq*4 + r] = s;
    }
  __syncthreads();

  // store P_u (fp16) and per-(row, ctile) aux
  #pragma unroll
  for (int j=0;j<4;j++){
    int c = ct*128 + wn*64 + j*16 + fl;
    #pragma unroll
    for (int i=0;i<4;i++){
      int q = qt*128 + wm*64 + i*16 + fq*4;
      #pragma unroll
      for (int r=0;r<4;r++)
        P[((long)hb*1024 + q + r)*1024 + c] = f2hs(acc[i][j][r]);
    }
  }
  if (fl == 0 && wn == 0){
    long aux = ((long)(hb*8 + ct))*1024 + qt*128;
    #pragma unroll
    for (int i=0;i<4;i++)
      #pragma unroll
      for (int r=0;r<4;r++){
        int row = wm*64 + i*16 + fq*4 + r;
        Mx[aux + row] = mt[i][r];
        Lx[aux + row] = red1[0][wm][row & 63] + red1[1][wm][row & 63];
      }
  }
}

// ---------------- attention stage 2: per-(hb,ct,q) softmax factor (fp16) ----------------
// f_ct[q] = exp(m_t - m_g) / l_g. 24576 threads.
__global__ void softmax_factor_kernel(const float* __restrict__ Mx, const float* __restrict__ Lx,
                                      short* __restrict__ Sc){
  int idx = blockIdx.x * 256 + threadIdx.x;
  int hb = idx >> 10, q = idx & 1023;
  float m[8], l[8];
  #pragma unroll
  for (int t=0;t<8;t++){
    long a = ((long)(hb*8 + t))*1024 + q;
    m[t] = Mx[a];
    l[t] = Lx[a];
  }
  float mg = m[0];
  #pragma unroll
  for (int t=1;t<8;t++) mg = fmaxf(mg, m[t]);
  float lg = 0.f;
  #pragma unroll
  for (int t=0;t<8;t++) lg += l[t] * __expf(m[t] - mg);
  float inv = 1.0f / lg;
  #pragma unroll
  for (int t=0;t<8;t++)
    Sc[((long)(hb*8 + t))*1024 + q] = f2hs(__expf(m[t] - mg) * inv);
}

// ---------------- attention stage 3: ctx = (f .* P_u) @ V^T, relu, store multi ----------------
// grid (8 qt, 6 et, 24 hb), 256 thr. Factor applied to A-fragments per ctile segment.
__global__ __launch_bounds__(256,2) void pv_kernel(
    const short* __restrict__ P, const short* __restrict__ Vtb,
    const short* __restrict__ Sc, short* __restrict__ multi)
{
  __shared__ short As[128*32];
  __shared__ short Bs[128*32];
  const int qt = blockIdx.x, et = blockIdx.y, hb = blockIdx.z;
  const int h = hb >> 3, b = hb & 7;
  const int tid = threadIdx.x, wave = tid>>6, lane = tid&63;
  const int wm = wave>>1, wn = wave&1;
  const int fl = lane&15, fq = lane>>4;
  const int srow = lane>>2;
  const int scol = (((lane&3) ^ (srow&3)))*8;
  const int aswz = ((fq ^ (fl&3)))*8;
  const short* Abase = P + (long)hb*1024*1024 + (long)(qt*128)*1024;
  const short* Bbase = Vtb + (long)hb*768*1024 + (long)(et*128)*1024;
  const short* scp = Sc + (long)(hb*8)*1024 + qt*128;

  f32x4 vz = {0.f,0.f,0.f,0.f};
  f32x4 acc[4][4];
  #pragma unroll
  for (int i=0;i<4;i++)
    #pragma unroll
    for (int j=0;j<4;j++) acc[i][j] = vz;

  for (int ct=0; ct<8; ct++){
    f16 s[4];
    #pragma unroll
    for (int i=0;i<4;i++)
      s[i] = __builtin_bit_cast(f16, scp[ct*1024 + wm*64 + i*16 + fl]);
    #pragma unroll
    for (int t=0;t<4;t++){
      const int kk = ct*128 + t*32;
      __syncthreads();
      #pragma unroll
      for (int r=0;r<2;r++){
        const int rb = r*64 + wave*16;
        GLL16(Abase + (long)(rb+srow)*1024 + kk + scol, As + rb*32);
        GLL16(Bbase + (long)(rb+srow)*1024 + kk + scol, Bs + rb*32);
      }
      __syncthreads();
      f16x8 a[4];
      #pragma unroll
      for (int i=0;i<4;i++){
        f16x8 av = *(const f16x8*)(As + (wm*64+i*16+fl)*32 + aswz);
        f16x8 sv;
        #pragma unroll
        for (int e=0;e<8;e++) sv[e] = s[i];
        a[i] = av * sv;
      }
      #pragma unroll
      for (int j=0;j<4;j++){
        f16x8 bv = *(const f16x8*)(Bs + (wn*64+j*16+fl)*32 + aswz);
        #pragma unroll
        for (int i=0;i<4;i++) acc[i][j] = mfma16(a[i], bv, acc[i][j]);
      }
    }
  }

  short* mp = multi + (long)(b*1024 + qt*128)*2304 + h*768 + et*128;
  #pragma unroll
  for (int j=0;j<4;j++){
    int e = wn*64 + j*16 + fl;
    #pragma unroll
    for (int i=0;i<4;i++){
      int q = wm*64 + i*16 + fq*4;
      #pragma unroll
      for (int r=0;r<4;r++)
        mp[(long)(q+r)*2304 + e] = f2hs(fmaxf(acc[i][j][r], 0.f));
    }
  }
}

// ---------------- final projection: relu(multi)[8192,2304] @ Wp + bp -> fp32 out ----------------
__global__ __launch_bounds__(256,2) void gemm_out_kernel(
    const short* __restrict__ A, const short* __restrict__ Bt,
    const float* __restrict__ bias, float* __restrict__ out)
{
  __shared__ short As[128*32];
  __shared__ short Bs[128*32];
  const int m0 = blockIdx.x*128, n0 = blockIdx.y*128;
  const int tid = threadIdx.x, wave = tid>>6, lane = tid&63;
  const int wm = wave>>1, wn = wave&1;
  const int fl = lane&15, fq = lane>>4;

  f32x4 vz = {0.f,0.f,0.f,0.f};
  f32x4 acc[4][4];
  #pragma unroll
  for (int i=0;i<4;i++)
    #pragma unroll
    for (int j=0;j<4;j++) acc[i][j] = vz;

  gemm_tile(A, Bt, 2304, m0, n0, As, Bs, acc);

  #pragma unroll
  for (int j=0;j<4;j++){
    int col = n0 + wn*64 + j*16 + fl;
    float bb = bias[col];
    #pragma unroll
    for (int i=0;i<4;i++){
      int row = m0 + wm*64 + i*16 + fq*4;
      #pragma unroll
      for (int r=0;r<4;r++)
        out[(long)(row+r)*768 + col] = acc[i][j][r] + bb;
    }
  }
}

extern "C" void kernel_launch(void* const* d_in, const int* in_sizes, int n_in,
                              void* d_out, int out_size, void* d_ws, size_t ws_size,
                              hipStream_t stream)
{
  const float* t1 = (const float*)d_in[0];
  const float* t2 = (const float*)d_in[1];
  const float* Wq = (const float*)d_in[2];
  const float* bq = (const float*)d_in[3];
  const float* Wk = (const float*)d_in[4];
  const float* bk = (const float*)d_in[5];
  const float* Wv = (const float*)d_in[6];
  const float* bv = (const float*)d_in[7];
  const float* Wp = (const float*)d_in[8];
  const float* bp = (const float*)d_in[9];
  float* out = (float*)d_out;

  char* ws = (char*)d_ws;
  size_t off = 0;
  auto carve = [&](size_t bytes){ void* p = ws + off; off += (bytes + 255) & ~(size_t)255; return p; };
  short* t1b = (short*)carve(8L*1024*768*2);
  short* t2b = (short*)carve(8L*1024*768*2);
  short* WqT = (short*)carve(3L*768*768*2);
  short* WkT = (short*)carve(3L*768*768*2);
  short* WvT = (short*)carve(3L*768*768*2);
  short* WpT = (short*)carve(768L*2304*2);
  short* Qb  = (short*)carve(3L*8192*768*2);
  short* Kb  = (short*)carve(3L*8192*768*2);
  short* Vtb = (short*)carve(3L*8*768*1024*2);    // [hb][e][lk]
  short* Pb  = (short*)carve(24L*1024*1024*2);    // [hb][q][c]
  float* Mx  = (float*)carve(24L*8*1024*4);       // [hb*8+ct][q]
  float* Lx  = (float*)carve(24L*8*1024*4);
  short* Scb = (short*)carve(24L*8*1024*2);       // fp16 factors [hb*8+ct][q]
  short* multib = Qb;   // alias: Qb dead after qk_exp; multi written by pv, read by gemm_out

  cvt2_f16_kernel<<<12288, 256, 0, stream>>>(t1, t2, t1b, t2b, 1572864);
  transpose_cvt_qkv_kernel<<<dim3(24,24,9), dim3(32,8), 0, stream>>>(Wq, Wk, Wv, WqT, WkT, WvT);
  transpose_cvt_kernel<<<dim3(24,72,1), dim3(32,8), 0, stream>>>(Wp, WpT, 2304, 768);
  gemm_qkv_kernel<<<dim3(64,6,9), 256, 0, stream>>>(t1b,t2b,WqT,WkT,WvT,bq,bk,bv,Qb,Kb,Vtb);
  qk_exp_kernel<<<dim3(8,8,24), 256, 0, stream>>>(Qb, Kb, Pb, Mx, Lx);
  softmax_factor_kernel<<<96, 256, 0, stream>>>(Mx, Lx, Scb);
  pv_kernel<<<dim3(8,6,24), 256, 0, stream>>>(Pb, Vtb, Scb, multib);
  gemm_out_kernel<<<dim3(64,6,1), 256, 0, stream>>>(multib, WpT, bp, out);
}